// Round 1
// baseline (317.254 us; speedup 1.0000x reference)
//
#include <hip/hip_runtime.h>

// NNConv GNN: 5 conv layers on a fixed graph (N=40000 nodes, E=400000 edges).
// Key factorization: W(e) = reshape(ea @ nn_w^T + nn_b, (fin,fout))
//   => x_src @ W(e) = ea0*(x_src@A0) + ea1*(x_src@A1) + (x_src@B)
// where A0[i][o]=nn_w[i*fout+o][0], A1=..[1], B[i][o]=nn_b[i*fout+o].
// So: per layer, precompute per-node Y0,Y1,Yb (+ x@root), then per-edge work
// is 3 FMAs per output channel. Mean-aggregate via CSR built once per launch.

#define NEG_SLOPE 0.01f

__global__ void zero2_kernel(int* __restrict__ a, int* __restrict__ b, int n) {
    int i = blockIdx.x * blockDim.x + threadIdx.x;
    if (i < n) { a[i] = 0; b[i] = 0; }
}

__global__ void count_kernel(const int* __restrict__ dst, int* __restrict__ counts, int E) {
    int e = blockIdx.x * blockDim.x + threadIdx.x;
    if (e < E) atomicAdd(&counts[dst[e]], 1);
}

// Single-block exclusive scan over counts[0..N) -> rowptr[0..N], plus invdeg.
__global__ void scan_kernel(const int* __restrict__ counts, int* __restrict__ rowptr,
                            float* __restrict__ invdeg, int N) {
    __shared__ int lds[1024];
    int t = threadIdx.x;
    int chunk = (N + 1023) >> 10;
    int beg = t * chunk;
    int end = beg + chunk; if (end > N) end = N;
    int s = 0;
    for (int i = beg; i < end; ++i) s += counts[i];
    lds[t] = s;
    __syncthreads();
    for (int d = 1; d < 1024; d <<= 1) {
        int v = (t >= d) ? lds[t - d] : 0;
        __syncthreads();
        lds[t] += v;
        __syncthreads();
    }
    int run = lds[t] - s;  // exclusive prefix
    for (int i = beg; i < end; ++i) {
        rowptr[i] = run;
        int c = counts[i];
        invdeg[i] = 1.0f / (float)(c > 1 ? c : 1);
        run += c;
    }
    if (t == 1023) rowptr[N] = lds[1023];
}

__global__ void fill_kernel(const int* __restrict__ src, const int* __restrict__ dst,
                            const float* __restrict__ ea,
                            const int* __restrict__ rowptr, int* __restrict__ cursor,
                            int* __restrict__ ssrc, float2* __restrict__ sea, int E) {
    int e = blockIdx.x * blockDim.x + threadIdx.x;
    if (e >= E) return;
    int d = dst[e];
    int p = rowptr[d] + atomicAdd(&cursor[d], 1);
    ssrc[p] = src[e];
    sea[p] = make_float2(ea[2 * e], ea[2 * e + 1]);
}

// Node-level precompute for fout=16 layers: Y[n][0..15]=x@A0, [16..31]=x@A1,
// [32..47]=x@B, [48..63]=x@root.  One thread per (node, o).
template <int FIN>
__global__ void node_pre16(const float* __restrict__ X, int ldx, int xoff,
                           const float* __restrict__ nnw, const float* __restrict__ nnb,
                           const float* __restrict__ root,
                           float* __restrict__ Y, int N) {
    int t = blockIdx.x * blockDim.x + threadIdx.x;
    int n = t >> 4, o = t & 15;
    if (n >= N) return;
    const float* xr = X + (size_t)n * ldx + xoff;
    float a0 = 0.f, a1 = 0.f, ab = 0.f, ar = 0.f;
#pragma unroll
    for (int i = 0; i < FIN; ++i) {
        float xv = xr[i];
        int k = i * 16 + o;
        a0 = fmaf(xv, nnw[2 * k], a0);
        a1 = fmaf(xv, nnw[2 * k + 1], a1);
        ab = fmaf(xv, nnb[k], ab);
        ar = fmaf(xv, root[k], ar);
    }
    float* y = Y + (size_t)n * 64;
    y[o] = a0; y[16 + o] = a1; y[32 + o] = ab; y[48 + o] = ar;
}

// Edge aggregation + epilogue (mean, +x@root, +bias, leaky relu) for fout=16.
__global__ void edge_agg16(const int* __restrict__ rowptr, const int* __restrict__ ssrc,
                           const float2* __restrict__ sea, const float* __restrict__ invdeg,
                           const float* __restrict__ Y, const float* __restrict__ bias,
                           float* __restrict__ Out, int outld, int outoff, int N) {
    int t = blockIdx.x * blockDim.x + threadIdx.x;
    int n = t >> 4, o = t & 15;
    if (n >= N) return;
    int beg = rowptr[n], end = rowptr[n + 1];
    float acc = 0.f;
    for (int k = beg; k < end; ++k) {
        int s = ssrc[k];
        float2 ea = sea[k];
        const float* ys = Y + (size_t)s * 64;
        acc = fmaf(ea.x, ys[o], acc);
        acc = fmaf(ea.y, ys[16 + o], acc);
        acc += ys[32 + o];
    }
    float r = acc * invdeg[n] + Y[(size_t)n * 64 + 48 + o] + bias[o];
    r = r > 0.f ? r : NEG_SLOPE * r;
    Out[(size_t)n * outld + outoff + o] = r;
}

// Final layer: fin=64, fout=2.  Y6[n][0..1]=A0, [2..3]=A1, [4..5]=B, [6..7]=root.
__global__ void node_pre2(const float* __restrict__ X5,
                          const float* __restrict__ nnw, const float* __restrict__ nnb,
                          const float* __restrict__ root,
                          float* __restrict__ Y6, int N) {
    int t = blockIdx.x * blockDim.x + threadIdx.x;
    int n = t >> 1, o = t & 1;
    if (n >= N) return;
    const float* xr = X5 + (size_t)n * 64;
    float a0 = 0.f, a1 = 0.f, ab = 0.f, ar = 0.f;
#pragma unroll
    for (int i = 0; i < 64; ++i) {
        float xv = xr[i];
        int k = i * 2 + o;
        a0 = fmaf(xv, nnw[2 * k], a0);
        a1 = fmaf(xv, nnw[2 * k + 1], a1);
        ab = fmaf(xv, nnb[k], ab);
        ar = fmaf(xv, root[k], ar);
    }
    float* y = Y6 + (size_t)n * 8;
    y[o] = a0; y[2 + o] = a1; y[4 + o] = ab; y[6 + o] = ar;
}

__global__ void edge_agg2(const int* __restrict__ rowptr, const int* __restrict__ ssrc,
                          const float2* __restrict__ sea, const float* __restrict__ invdeg,
                          const float* __restrict__ Y6, const float* __restrict__ bias,
                          float* __restrict__ Out, int N) {
    int t = blockIdx.x * blockDim.x + threadIdx.x;
    int n = t >> 1, o = t & 1;
    if (n >= N) return;
    int beg = rowptr[n], end = rowptr[n + 1];
    float acc = 0.f;
    for (int k = beg; k < end; ++k) {
        int s = ssrc[k];
        float2 ea = sea[k];
        const float* ys = Y6 + (size_t)s * 8;
        acc = fmaf(ea.x, ys[o], acc);
        acc = fmaf(ea.y, ys[2 + o], acc);
        acc += ys[4 + o];
    }
    // final layer: no leaky relu
    Out[(size_t)n * 2 + o] = acc * invdeg[n] + Y6[(size_t)n * 8 + 6 + o] + bias[o];
}

extern "C" void kernel_launch(void* const* d_in, const int* in_sizes, int n_in,
                              void* d_out, int out_size, void* d_ws, size_t ws_size,
                              hipStream_t stream) {
    const float* x        = (const float*)d_in[0];
    const int*   eidx     = (const int*)d_in[1];
    const float* eattr    = (const float*)d_in[2];
    const float* nn1_w    = (const float*)d_in[3];
    const float* nn1_b    = (const float*)d_in[4];
    const float* root1    = (const float*)d_in[5];
    const float* bias1    = (const float*)d_in[6];
    const float* nn2_w    = (const float*)d_in[7];
    const float* nn2_b    = (const float*)d_in[8];
    const float* root2    = (const float*)d_in[9];
    const float* bias2    = (const float*)d_in[10];
    const float* nn3_w    = (const float*)d_in[11];
    const float* nn3_b    = (const float*)d_in[12];
    const float* root3    = (const float*)d_in[13];
    const float* bias3    = (const float*)d_in[14];
    float* out = (float*)d_out;

    const int N = in_sizes[0] / 2;
    const int E = in_sizes[2] / 2;
    const int* src = eidx;
    const int* dst = eidx + E;

    // workspace layout
    char* ws = (char*)d_ws;
    size_t off = 0;
    auto alloc = [&](size_t bytes, size_t align) -> char* {
        off = (off + align - 1) / align * align;
        char* p = ws + off;
        off += bytes;
        return p;
    };
    int*    rowptr  = (int*)alloc((size_t)(N + 1) * 4, 16);
    int*    cursor  = (int*)alloc((size_t)N * 4, 16);
    int*    counts  = (int*)alloc((size_t)N * 4, 16);
    float*  invdeg  = (float*)alloc((size_t)N * 4, 16);
    int*    ssrc    = (int*)alloc((size_t)E * 4, 16);
    float2* sea     = (float2*)alloc((size_t)E * 8, 16);
    float*  Y       = (float*)alloc((size_t)N * 64 * 4, 16);
    float*  X5      = (float*)alloc((size_t)N * 64 * 4, 16);
    float*  Y6      = (float*)alloc((size_t)N * 8 * 4, 16);
    (void)ws_size; (void)n_in; (void)out_size;

    const int B = 256;
    auto blocks = [&](int threads) { return (threads + B - 1) / B; };

    // --- CSR build ---
    zero2_kernel<<<blocks(N), B, 0, stream>>>(counts, cursor, N);
    count_kernel<<<blocks(E), B, 0, stream>>>(dst, counts, E);
    scan_kernel<<<1, 1024, 0, stream>>>(counts, rowptr, invdeg, N);
    fill_kernel<<<blocks(E), B, 0, stream>>>(src, dst, eattr, rowptr, cursor, ssrc, sea, E);

    // --- layer 1: fin=2 -> X5 cols [0,16) ---
    node_pre16<2><<<blocks(N * 16), B, 0, stream>>>(x, 2, 0, nn1_w, nn1_b, root1, Y, N);
    edge_agg16<<<blocks(N * 16), B, 0, stream>>>(rowptr, ssrc, sea, invdeg, Y, bias1, X5, 64, 0, N);

    // --- layers 2-4: fin=16, shared nn2/root2/bias2 ---
    for (int l = 0; l < 3; ++l) {
        int xoff = l * 16;
        node_pre16<16><<<blocks(N * 16), B, 0, stream>>>(X5, 64, xoff, nn2_w, nn2_b, root2, Y, N);
        edge_agg16<<<blocks(N * 16), B, 0, stream>>>(rowptr, ssrc, sea, invdeg, Y, bias2, X5, 64, xoff + 16, N);
    }

    // --- layer 6: fin=64, fout=2, no lrelu ---
    node_pre2<<<blocks(N * 2), B, 0, stream>>>(X5, nn3_w, nn3_b, root3, Y6, N);
    edge_agg2<<<blocks(N * 2), B, 0, stream>>>(rowptr, ssrc, sea, invdeg, Y6, bias3, out, N);
}

// Round 5
// 228.067 us; speedup vs baseline: 1.3911x; 1.3911x over previous
//
#include <hip/hip_runtime.h>

// NNConv GNN: 5 conv layers on a fixed graph (N=40000 nodes, E=400000 edges).
// Factorization: W(e) = reshape(ea @ nn_w^T + nn_b, (fin,fout))
//   => x_src @ W(e) = ea0*(x_src@A0) + ea1*(x_src@A1) + (x_src@B)
// Per layer: precompute per-node Y0,Y1,Yb (+ x@root), then per-edge work is
// 3 FMAs per output channel. Mean-aggregate via CSR built once per launch.
// R1: single-block scan (90us, 29% of total) -> 3-stage hierarchical scan;
//     pack (src, ea0, ea1) into one float4 per edge.
// R2/R3/R4: resubmit (container died before benching).

#define NEG_SLOPE 0.01f
#define SB 256  // scan block size

__global__ void zero2_kernel(int* __restrict__ a, int* __restrict__ b, int n) {
    int i = blockIdx.x * blockDim.x + threadIdx.x;
    if (i < n) { a[i] = 0; b[i] = 0; }
}

__global__ void count_kernel(const int* __restrict__ dst, int* __restrict__ counts, int E) {
    int e = blockIdx.x * blockDim.x + threadIdx.x;
    if (e < E) atomicAdd(&counts[dst[e]], 1);
}

// Stage 1: per-block sums of counts.
__global__ void blocksum_kernel(const int* __restrict__ counts, int* __restrict__ bsum, int N) {
    int i = blockIdx.x * SB + threadIdx.x;
    int v = (i < N) ? counts[i] : 0;
#pragma unroll
    for (int d = 32; d; d >>= 1) v += __shfl_down(v, d);
    __shared__ int wsum[SB / 64];
    int lane = threadIdx.x & 63, w = threadIdx.x >> 6;
    if (lane == 0) wsum[w] = v;
    __syncthreads();
    if (threadIdx.x == 0) {
        int s = 0;
#pragma unroll
        for (int k = 0; k < SB / 64; ++k) s += wsum[k];
        bsum[blockIdx.x] = s;
    }
}

// Stage 2: one small block scans the block sums (NB <= 256); writes rowptr[N].
__global__ void scanbsum_kernel(const int* __restrict__ bsum, int* __restrict__ boff,
                                int* __restrict__ rowptr_last, int NB) {
    __shared__ int lds[SB];
    int t = threadIdx.x;
    int v = (t < NB) ? bsum[t] : 0;
    lds[t] = v;
    __syncthreads();
    for (int d = 1; d < SB; d <<= 1) {
        int u = (t >= d) ? lds[t - d] : 0;
        __syncthreads();
        lds[t] += u;
        __syncthreads();
    }
    if (t < NB) boff[t] = lds[t] - v;  // exclusive prefix
    if (t == SB - 1) rowptr_last[0] = lds[SB - 1];  // total = E
}

// Stage 3: in-block exclusive scan + block offset -> rowptr, invdeg.
__global__ void writeptr_kernel(const int* __restrict__ counts, const int* __restrict__ boff,
                                int* __restrict__ rowptr, float* __restrict__ invdeg, int N) {
    __shared__ int lds[SB];
    int t = threadIdx.x;
    int i = blockIdx.x * SB + t;
    int c = (i < N) ? counts[i] : 0;
    lds[t] = c;
    __syncthreads();
    for (int d = 1; d < SB; d <<= 1) {
        int u = (t >= d) ? lds[t - d] : 0;
        __syncthreads();
        lds[t] += u;
        __syncthreads();
    }
    if (i < N) {
        rowptr[i] = lds[t] - c + boff[blockIdx.x];
        invdeg[i] = 1.0f / (float)(c > 1 ? c : 1);
    }
}

__global__ void fill_kernel(const int* __restrict__ src, const int* __restrict__ dst,
                            const float* __restrict__ ea,
                            const int* __restrict__ rowptr, int* __restrict__ cursor,
                            float4* __restrict__ edata, int E) {
    int e = blockIdx.x * blockDim.x + threadIdx.x;
    if (e >= E) return;
    int d = dst[e];
    int p = rowptr[d] + atomicAdd(&cursor[d], 1);
    edata[p] = make_float4(__int_as_float(src[e]), ea[2 * e], ea[2 * e + 1], 0.f);
}

// Node-level precompute for fout=16 layers: Y[n][0..15]=x@A0, [16..31]=x@A1,
// [32..47]=x@B, [48..63]=x@root.  One thread per (node, o).
template <int FIN>
__global__ void node_pre16(const float* __restrict__ X, int ldx, int xoff,
                           const float* __restrict__ nnw, const float* __restrict__ nnb,
                           const float* __restrict__ root,
                           float* __restrict__ Y, int N) {
    int t = blockIdx.x * blockDim.x + threadIdx.x;
    int n = t >> 4, o = t & 15;
    if (n >= N) return;
    const float* xr = X + (size_t)n * ldx + xoff;
    float a0 = 0.f, a1 = 0.f, ab = 0.f, ar = 0.f;
#pragma unroll
    for (int i = 0; i < FIN; ++i) {
        float xv = xr[i];
        int k = i * 16 + o;
        a0 = fmaf(xv, nnw[2 * k], a0);
        a1 = fmaf(xv, nnw[2 * k + 1], a1);
        ab = fmaf(xv, nnb[k], ab);
        ar = fmaf(xv, root[k], ar);
    }
    float* y = Y + (size_t)n * 64;
    y[o] = a0; y[16 + o] = a1; y[32 + o] = ab; y[48 + o] = ar;
}

// Edge aggregation + epilogue (mean, +x@root, +bias, leaky relu) for fout=16.
__global__ void edge_agg16(const int* __restrict__ rowptr, const float4* __restrict__ edata,
                           const float* __restrict__ invdeg,
                           const float* __restrict__ Y, const float* __restrict__ bias,
                           float* __restrict__ Out, int outld, int outoff, int N) {
    int t = blockIdx.x * blockDim.x + threadIdx.x;
    int n = t >> 4, o = t & 15;
    if (n >= N) return;
    int beg = rowptr[n], end = rowptr[n + 1];
    float acc = 0.f;
    for (int k = beg; k < end; ++k) {
        float4 ed = edata[k];
        int s = __float_as_int(ed.x);
        const float* ys = Y + (size_t)s * 64;
        acc = fmaf(ed.y, ys[o], acc);
        acc = fmaf(ed.z, ys[16 + o], acc);
        acc += ys[32 + o];
    }
    float r = acc * invdeg[n] + Y[(size_t)n * 64 + 48 + o] + bias[o];
    r = r > 0.f ? r : NEG_SLOPE * r;
    Out[(size_t)n * outld + outoff + o] = r;
}

// Final layer: fin=64, fout=2.  Y6[n][0..1]=A0, [2..3]=A1, [4..5]=B, [6..7]=root.
__global__ void node_pre2(const float* __restrict__ X5,
                          const float* __restrict__ nnw, const float* __restrict__ nnb,
                          const float* __restrict__ root,
                          float* __restrict__ Y6, int N) {
    int t = blockIdx.x * blockDim.x + threadIdx.x;
    int n = t >> 1, o = t & 1;
    if (n >= N) return;
    const float* xr = X5 + (size_t)n * 64;
    float a0 = 0.f, a1 = 0.f, ab = 0.f, ar = 0.f;
#pragma unroll
    for (int i = 0; i < 64; ++i) {
        float xv = xr[i];
        int k = i * 2 + o;
        a0 = fmaf(xv, nnw[2 * k], a0);
        a1 = fmaf(xv, nnw[2 * k + 1], a1);
        ab = fmaf(xv, nnb[k], ab);
        ar = fmaf(xv, root[k], ar);
    }
    float* y = Y6 + (size_t)n * 8;
    y[o] = a0; y[2 + o] = a1; y[4 + o] = ab; y[6 + o] = ar;
}

__global__ void edge_agg2(const int* __restrict__ rowptr, const float4* __restrict__ edata,
                          const float* __restrict__ invdeg,
                          const float* __restrict__ Y6, const float* __restrict__ bias,
                          float* __restrict__ Out, int N) {
    int t = blockIdx.x * blockDim.x + threadIdx.x;
    int n = t >> 1, o = t & 1;
    if (n >= N) return;
    int beg = rowptr[n], end = rowptr[n + 1];
    float acc = 0.f;
    for (int k = beg; k < end; ++k) {
        float4 ed = edata[k];
        int s = __float_as_int(ed.x);
        const float* ys = Y6 + (size_t)s * 8;
        acc = fmaf(ed.y, ys[o], acc);
        acc = fmaf(ed.z, ys[2 + o], acc);
        acc += ys[4 + o];
    }
    // final layer: no leaky relu
    Out[(size_t)n * 2 + o] = acc * invdeg[n] + Y6[(size_t)n * 8 + 6 + o] + bias[o];
}

extern "C" void kernel_launch(void* const* d_in, const int* in_sizes, int n_in,
                              void* d_out, int out_size, void* d_ws, size_t ws_size,
                              hipStream_t stream) {
    const float* x        = (const float*)d_in[0];
    const int*   eidx     = (const int*)d_in[1];
    const float* eattr    = (const float*)d_in[2];
    const float* nn1_w    = (const float*)d_in[3];
    const float* nn1_b    = (const float*)d_in[4];
    const float* root1    = (const float*)d_in[5];
    const float* bias1    = (const float*)d_in[6];
    const float* nn2_w    = (const float*)d_in[7];
    const float* nn2_b    = (const float*)d_in[8];
    const float* root2    = (const float*)d_in[9];
    const float* bias2    = (const float*)d_in[10];
    const float* nn3_w    = (const float*)d_in[11];
    const float* nn3_b    = (const float*)d_in[12];
    const float* root3    = (const float*)d_in[13];
    const float* bias3    = (const float*)d_in[14];
    float* out = (float*)d_out;

    const int N = in_sizes[0] / 2;
    const int E = in_sizes[2] / 2;
    const int* src = eidx;
    const int* dst = eidx + E;
    const int NB = (N + SB - 1) / SB;  // 157 for N=40000 (must be <= 256)

    // workspace layout
    char* ws = (char*)d_ws;
    size_t off = 0;
    auto alloc = [&](size_t bytes, size_t align) -> char* {
        off = (off + align - 1) / align * align;
        char* p = ws + off;
        off += bytes;
        return p;
    };
    int*    rowptr  = (int*)alloc((size_t)(N + 1) * 4, 16);
    int*    cursor  = (int*)alloc((size_t)N * 4, 16);
    int*    counts  = (int*)alloc((size_t)N * 4, 16);
    float*  invdeg  = (float*)alloc((size_t)N * 4, 16);
    int*    bsum    = (int*)alloc((size_t)SB * 4, 16);
    int*    boff    = (int*)alloc((size_t)SB * 4, 16);
    float4* edata   = (float4*)alloc((size_t)E * 16, 16);
    float*  Y       = (float*)alloc((size_t)N * 64 * 4, 16);
    float*  X5      = (float*)alloc((size_t)N * 64 * 4, 16);
    float*  Y6      = (float*)alloc((size_t)N * 8 * 4, 16);
    (void)ws_size; (void)n_in; (void)out_size;

    const int B = 256;
    auto blocks = [&](int threads) { return (threads + B - 1) / B; };

    // --- CSR build ---
    zero2_kernel<<<blocks(N), B, 0, stream>>>(counts, cursor, N);
    count_kernel<<<blocks(E), B, 0, stream>>>(dst, counts, E);
    blocksum_kernel<<<NB, SB, 0, stream>>>(counts, bsum, N);
    scanbsum_kernel<<<1, SB, 0, stream>>>(bsum, boff, rowptr + N, NB);
    writeptr_kernel<<<NB, SB, 0, stream>>>(counts, boff, rowptr, invdeg, N);
    fill_kernel<<<blocks(E), B, 0, stream>>>(src, dst, eattr, rowptr, cursor, edata, E);

    // --- layer 1: fin=2 -> X5 cols [0,16) ---
    node_pre16<2><<<blocks(N * 16), B, 0, stream>>>(x, 2, 0, nn1_w, nn1_b, root1, Y, N);
    edge_agg16<<<blocks(N * 16), B, 0, stream>>>(rowptr, edata, invdeg, Y, bias1, X5, 64, 0, N);

    // --- layers 2-4: fin=16, shared nn2/root2/bias2 ---
    for (int l = 0; l < 3; ++l) {
        int xoff = l * 16;
        node_pre16<16><<<blocks(N * 16), B, 0, stream>>>(X5, 64, xoff, nn2_w, nn2_b, root2, Y, N);
        edge_agg16<<<blocks(N * 16), B, 0, stream>>>(rowptr, edata, invdeg, Y, bias2, X5, 64, xoff + 16, N);
    }

    // --- layer 6: fin=64, fout=2, no lrelu ---
    node_pre2<<<blocks(N * 2), B, 0, stream>>>(X5, nn3_w, nn3_b, root3, Y6, N);
    edge_agg2<<<blocks(N * 2), B, 0, stream>>>(rowptr, edata, invdeg, Y6, bias3, out, N);
}

// Round 7
// 204.872 us; speedup vs baseline: 1.5486x; 1.1132x over previous
//
#include <hip/hip_runtime.h>

// NNConv GNN: 5 conv layers on a fixed graph (N=40000 nodes, E=400000 edges).
// Factorization: W(e) = reshape(ea @ nn_w^T + nn_b, (fin,fout))
//   => x_src @ W(e) = ea0*(x_src@A0) + ea1*(x_src@A1) + (x_src@B)
// Per layer: precompute per-node Y0,Y1,Yb (+ x@root), then per-edge work is
// 3 FMAs per output channel. Mean-aggregate via CSR built once per launch.
// R1: single-block scan -> 3-stage hierarchical scan (317->228us, matched).
// R5: wave-per-node aggregation (4 edges/iter via 64 lanes = 4 groups x 16ch,
//     shfl_xor reduce) to break the dependent-load chain; slot recorded in
//     count_kernel kills fill's cursor atomics.
// R6: resubmit (container died before benching).

#define NEG_SLOPE 0.01f
#define SB 256  // scan block size

__global__ void zero1_kernel(int* __restrict__ a, int n) {
    int i = blockIdx.x * blockDim.x + threadIdx.x;
    if (i < n) a[i] = 0;
}

// counts via atomics; atomic return value = this edge's slot within its node.
__global__ void count_kernel(const int* __restrict__ dst, int* __restrict__ counts,
                             int* __restrict__ slot, int E) {
    int e = blockIdx.x * blockDim.x + threadIdx.x;
    if (e < E) slot[e] = atomicAdd(&counts[dst[e]], 1);
}

// Stage 1: per-block sums of counts.
__global__ void blocksum_kernel(const int* __restrict__ counts, int* __restrict__ bsum, int N) {
    int i = blockIdx.x * SB + threadIdx.x;
    int v = (i < N) ? counts[i] : 0;
#pragma unroll
    for (int d = 32; d; d >>= 1) v += __shfl_down(v, d);
    __shared__ int wsum[SB / 64];
    int lane = threadIdx.x & 63, w = threadIdx.x >> 6;
    if (lane == 0) wsum[w] = v;
    __syncthreads();
    if (threadIdx.x == 0) {
        int s = 0;
#pragma unroll
        for (int k = 0; k < SB / 64; ++k) s += wsum[k];
        bsum[blockIdx.x] = s;
    }
}

// Stage 2: one small block scans the block sums (NB <= 256); writes rowptr[N].
__global__ void scanbsum_kernel(const int* __restrict__ bsum, int* __restrict__ boff,
                                int* __restrict__ rowptr_last, int NB) {
    __shared__ int lds[SB];
    int t = threadIdx.x;
    int v = (t < NB) ? bsum[t] : 0;
    lds[t] = v;
    __syncthreads();
    for (int d = 1; d < SB; d <<= 1) {
        int u = (t >= d) ? lds[t - d] : 0;
        __syncthreads();
        lds[t] += u;
        __syncthreads();
    }
    if (t < NB) boff[t] = lds[t] - v;  // exclusive prefix
    if (t == SB - 1) rowptr_last[0] = lds[SB - 1];  // total = E
}

// Stage 3: in-block exclusive scan + block offset -> rowptr, invdeg.
__global__ void writeptr_kernel(const int* __restrict__ counts, const int* __restrict__ boff,
                                int* __restrict__ rowptr, float* __restrict__ invdeg, int N) {
    __shared__ int lds[SB];
    int t = threadIdx.x;
    int i = blockIdx.x * SB + t;
    int c = (i < N) ? counts[i] : 0;
    lds[t] = c;
    __syncthreads();
    for (int d = 1; d < SB; d <<= 1) {
        int u = (t >= d) ? lds[t - d] : 0;
        __syncthreads();
        lds[t] += u;
        __syncthreads();
    }
    if (i < N) {
        rowptr[i] = lds[t] - c + boff[blockIdx.x];
        invdeg[i] = 1.0f / (float)(c > 1 ? c : 1);
    }
}

// No atomics: position = rowptr[dst] + slot recorded during count.
__global__ void fill_kernel(const int* __restrict__ src, const int* __restrict__ dst,
                            const float* __restrict__ ea,
                            const int* __restrict__ rowptr, const int* __restrict__ slot,
                            float4* __restrict__ edata, int E) {
    int e = blockIdx.x * blockDim.x + threadIdx.x;
    if (e >= E) return;
    int p = rowptr[dst[e]] + slot[e];
    edata[p] = make_float4(__int_as_float(src[e]), ea[2 * e], ea[2 * e + 1], 0.f);
}

// Node-level precompute for fout=16 layers: Y[n][0..15]=x@A0, [16..31]=x@A1,
// [32..47]=x@B, [48..63]=x@root.  One thread per (node, o).
template <int FIN>
__global__ void node_pre16(const float* __restrict__ X, int ldx, int xoff,
                           const float* __restrict__ nnw, const float* __restrict__ nnb,
                           const float* __restrict__ root,
                           float* __restrict__ Y, int N) {
    int t = blockIdx.x * blockDim.x + threadIdx.x;
    int n = t >> 4, o = t & 15;
    if (n >= N) return;
    const float* xr = X + (size_t)n * ldx + xoff;
    float a0 = 0.f, a1 = 0.f, ab = 0.f, ar = 0.f;
#pragma unroll
    for (int i = 0; i < FIN; ++i) {
        float xv = xr[i];
        int k = i * 16 + o;
        a0 = fmaf(xv, nnw[2 * k], a0);
        a1 = fmaf(xv, nnw[2 * k + 1], a1);
        ab = fmaf(xv, nnb[k], ab);
        ar = fmaf(xv, root[k], ar);
    }
    float* y = Y + (size_t)n * 64;
    y[o] = a0; y[16 + o] = a1; y[32 + o] = ab; y[48 + o] = ar;
}

// Wave-per-node aggregation, fout=16: 64 lanes = 4 edge-groups x 16 channels.
// Each group takes edges beg+g, beg+g+4, ...; shfl_xor(16,32) folds groups.
__global__ void edge_agg16_wave(const int* __restrict__ rowptr, const float4* __restrict__ edata,
                                const float* __restrict__ invdeg,
                                const float* __restrict__ Y, const float* __restrict__ bias,
                                float* __restrict__ Out, int outld, int outoff, int N) {
    int w = (int)((blockIdx.x * blockDim.x + threadIdx.x) >> 6);
    if (w >= N) return;
    int lane = threadIdx.x & 63;
    int o = lane & 15, g = lane >> 4;
    int beg = rowptr[w], end = rowptr[w + 1];
    float acc = 0.f;
    for (int k = beg + g; k < end; k += 4) {
        float4 ed = edata[k];
        int s = __float_as_int(ed.x);
        const float* ys = Y + (size_t)s * 64;
        acc += fmaf(ed.y, ys[o], fmaf(ed.z, ys[16 + o], ys[32 + o]));
    }
    acc += __shfl_xor(acc, 16, 64);
    acc += __shfl_xor(acc, 32, 64);
    float r = acc * invdeg[w] + Y[(size_t)w * 64 + 48 + o] + bias[o];
    r = r > 0.f ? r : NEG_SLOPE * r;
    if (lane < 16) Out[(size_t)w * outld + outoff + o] = r;
}

// Final layer: fin=64, fout=2.  Y6[n][0..1]=A0, [2..3]=A1, [4..5]=B, [6..7]=root.
__global__ void node_pre2(const float* __restrict__ X5,
                          const float* __restrict__ nnw, const float* __restrict__ nnb,
                          const float* __restrict__ root,
                          float* __restrict__ Y6, int N) {
    int t = blockIdx.x * blockDim.x + threadIdx.x;
    int n = t >> 1, o = t & 1;
    if (n >= N) return;
    const float* xr = X5 + (size_t)n * 64;
    float a0 = 0.f, a1 = 0.f, ab = 0.f, ar = 0.f;
#pragma unroll
    for (int i = 0; i < 64; ++i) {
        float xv = xr[i];
        int k = i * 2 + o;
        a0 = fmaf(xv, nnw[2 * k], a0);
        a1 = fmaf(xv, nnw[2 * k + 1], a1);
        ab = fmaf(xv, nnb[k], ab);
        ar = fmaf(xv, root[k], ar);
    }
    float* y = Y6 + (size_t)n * 8;
    y[o] = a0; y[2 + o] = a1; y[4 + o] = ab; y[6 + o] = ar;
}

// Wave-per-node aggregation, fout=2: 64 lanes = 32 edge-groups x 2 channels.
__global__ void edge_agg2_wave(const int* __restrict__ rowptr, const float4* __restrict__ edata,
                               const float* __restrict__ invdeg,
                               const float* __restrict__ Y6, const float* __restrict__ bias,
                               float* __restrict__ Out, int N) {
    int w = (int)((blockIdx.x * blockDim.x + threadIdx.x) >> 6);
    if (w >= N) return;
    int lane = threadIdx.x & 63;
    int o = lane & 1, g = lane >> 1;
    int beg = rowptr[w], end = rowptr[w + 1];
    float acc = 0.f;
    for (int k = beg + g; k < end; k += 32) {
        float4 ed = edata[k];
        int s = __float_as_int(ed.x);
        const float* ys = Y6 + (size_t)s * 8;
        acc += fmaf(ed.y, ys[o], fmaf(ed.z, ys[2 + o], ys[4 + o]));
    }
#pragma unroll
    for (int m = 2; m <= 32; m <<= 1) acc += __shfl_xor(acc, m, 64);
    // final layer: no leaky relu
    if (lane < 2) Out[(size_t)w * 2 + o] = acc * invdeg[w] + Y6[(size_t)w * 8 + 6 + o] + bias[o];
}

extern "C" void kernel_launch(void* const* d_in, const int* in_sizes, int n_in,
                              void* d_out, int out_size, void* d_ws, size_t ws_size,
                              hipStream_t stream) {
    const float* x        = (const float*)d_in[0];
    const int*   eidx     = (const int*)d_in[1];
    const float* eattr    = (const float*)d_in[2];
    const float* nn1_w    = (const float*)d_in[3];
    const float* nn1_b    = (const float*)d_in[4];
    const float* root1    = (const float*)d_in[5];
    const float* bias1    = (const float*)d_in[6];
    const float* nn2_w    = (const float*)d_in[7];
    const float* nn2_b    = (const float*)d_in[8];
    const float* root2    = (const float*)d_in[9];
    const float* bias2    = (const float*)d_in[10];
    const float* nn3_w    = (const float*)d_in[11];
    const float* nn3_b    = (const float*)d_in[12];
    const float* root3    = (const float*)d_in[13];
    const float* bias3    = (const float*)d_in[14];
    float* out = (float*)d_out;

    const int N = in_sizes[0] / 2;
    const int E = in_sizes[2] / 2;
    const int* src = eidx;
    const int* dst = eidx + E;
    const int NB = (N + SB - 1) / SB;  // 157 for N=40000 (must be <= 256)

    // workspace layout
    char* ws = (char*)d_ws;
    size_t off = 0;
    auto alloc = [&](size_t bytes, size_t align) -> char* {
        off = (off + align - 1) / align * align;
        char* p = ws + off;
        off += bytes;
        return p;
    };
    int*    rowptr  = (int*)alloc((size_t)(N + 1) * 4, 16);
    int*    counts  = (int*)alloc((size_t)N * 4, 16);
    float*  invdeg  = (float*)alloc((size_t)N * 4, 16);
    int*    slot    = (int*)alloc((size_t)E * 4, 16);
    int*    bsum    = (int*)alloc((size_t)SB * 4, 16);
    int*    boff    = (int*)alloc((size_t)SB * 4, 16);
    float4* edata   = (float4*)alloc((size_t)E * 16, 16);
    float*  Y       = (float*)alloc((size_t)N * 64 * 4, 16);
    float*  X5      = (float*)alloc((size_t)N * 64 * 4, 16);
    float*  Y6      = (float*)alloc((size_t)N * 8 * 4, 16);
    (void)ws_size; (void)n_in; (void)out_size;

    const int B = 256;
    auto blocks = [&](int threads) { return (threads + B - 1) / B; };
    const int waveblocks = (N * 64 + B - 1) / B;  // one wave (64 lanes) per node

    // --- CSR build ---
    zero1_kernel<<<blocks(N), B, 0, stream>>>(counts, N);
    count_kernel<<<blocks(E), B, 0, stream>>>(dst, counts, slot, E);
    blocksum_kernel<<<NB, SB, 0, stream>>>(counts, bsum, N);
    scanbsum_kernel<<<1, SB, 0, stream>>>(bsum, boff, rowptr + N, NB);
    writeptr_kernel<<<NB, SB, 0, stream>>>(counts, boff, rowptr, invdeg, N);
    fill_kernel<<<blocks(E), B, 0, stream>>>(src, dst, eattr, rowptr, slot, edata, E);

    // --- layer 1: fin=2 -> X5 cols [0,16) ---
    node_pre16<2><<<blocks(N * 16), B, 0, stream>>>(x, 2, 0, nn1_w, nn1_b, root1, Y, N);
    edge_agg16_wave<<<waveblocks, B, 0, stream>>>(rowptr, edata, invdeg, Y, bias1, X5, 64, 0, N);

    // --- layers 2-4: fin=16, shared nn2/root2/bias2 ---
    for (int l = 0; l < 3; ++l) {
        int xoff = l * 16;
        node_pre16<16><<<blocks(N * 16), B, 0, stream>>>(X5, 64, xoff, nn2_w, nn2_b, root2, Y, N);
        edge_agg16_wave<<<waveblocks, B, 0, stream>>>(rowptr, edata, invdeg, Y, bias2, X5, 64, xoff + 16, N);
    }

    // --- layer 6: fin=64, fout=2, no lrelu ---
    node_pre2<<<blocks(N * 2), B, 0, stream>>>(X5, nn3_w, nn3_b, root3, Y6, N);
    edge_agg2_wave<<<waveblocks, B, 0, stream>>>(rowptr, edata, invdeg, Y6, bias3, out, N);
}

// Round 9
// 189.961 us; speedup vs baseline: 1.6701x; 1.0785x over previous
//
#include <hip/hip_runtime.h>

// NNConv GNN: 5 conv layers, fixed graph (N=40000, E=400000).
// W(e) factorization => per-node Y = [x@A0 | x@A1 | x@B | x@root], per-edge
// work = 3 FMAs/channel; mean-aggregate via CSR built per launch.
// R1: hierarchical scan (317->228us). R5: wave-per-node agg (228->205us).
// R7: fused agg+next-pre (FAILED absmax 9.2e-2; suspects: ws overflow 40.5MB,
//     divergent shfl in pre6).
// R8: drop X5 entirely -- final-layer projections accumulated incrementally
//     per layer from wave-resident r (uniform shfl only). Footprint back to
//     30.24MB (=R5's proven bound). 9 dispatches.

#define NEG_SLOPE 0.01f
#define SB 256

__global__ void zero1_kernel(int* __restrict__ a, int n) {
    int i = blockIdx.x * blockDim.x + threadIdx.x;
    if (i < n) a[i] = 0;
}

// counts via atomics; atomic return value = this edge's slot within its node.
__global__ void count_kernel(const int* __restrict__ dst, int* __restrict__ counts,
                             int* __restrict__ slot, int E) {
    int e = blockIdx.x * blockDim.x + threadIdx.x;
    if (e < E) slot[e] = atomicAdd(&counts[dst[e]], 1);
}

// One-kernel scan: each block redundantly sums counts[0..base) for its offset
// (L2-resident), then LDS-scans its own tile.
__global__ void scanall_kernel(const int* __restrict__ counts, int* __restrict__ rowptr,
                               float* __restrict__ invdeg, int N) {
    int t = threadIdx.x;
    int base = blockIdx.x * SB;
    int part = 0;
    for (int i = t; i < base; i += SB) part += counts[i];
    __shared__ int red[SB];
    red[t] = part; __syncthreads();
    for (int d = SB / 2; d; d >>= 1) { if (t < d) red[t] += red[t + d]; __syncthreads(); }
    int offset = red[0];
    __syncthreads();
    int i = base + t;
    int c = (i < N) ? counts[i] : 0;
    __shared__ int lds[SB];
    lds[t] = c; __syncthreads();
    for (int d = 1; d < SB; d <<= 1) {
        int u = (t >= d) ? lds[t - d] : 0;
        __syncthreads();
        lds[t] += u;
        __syncthreads();
    }
    if (i < N) {
        rowptr[i] = offset + lds[t] - c;
        invdeg[i] = 1.0f / (float)(c > 1 ? c : 1);
        if (i == N - 1) rowptr[N] = offset + lds[t];
    }
}

// Horizontal fusion: blocks [0,nFill) scatter edges into edata;
// blocks [nFill,...) compute layer-1 node projections (fin=2) into Y.
__global__ void fill_pre1_kernel(const int* __restrict__ src, const int* __restrict__ dst,
                                 const float* __restrict__ ea,
                                 const int* __restrict__ rowptr, const int* __restrict__ slot,
                                 float4* __restrict__ edata, int E, int nFill,
                                 const float* __restrict__ x,
                                 const float* __restrict__ nnw, const float* __restrict__ nnb,
                                 const float* __restrict__ root,
                                 float* __restrict__ Y, int N) {
    if ((int)blockIdx.x < nFill) {
        int e = blockIdx.x * blockDim.x + threadIdx.x;
        if (e >= E) return;
        int p = rowptr[dst[e]] + slot[e];
        edata[p] = make_float4(__int_as_float(src[e]), ea[2 * e], ea[2 * e + 1], 0.f);
    } else {
        int t = (blockIdx.x - nFill) * blockDim.x + threadIdx.x;
        int n = t >> 4, o = t & 15;
        if (n >= N) return;
        float x0 = x[n * 2], x1 = x[n * 2 + 1];
        int k0 = o, k1 = 16 + o;
        float a0 = x0 * nnw[2 * k0] + x1 * nnw[2 * k1];
        float a1 = x0 * nnw[2 * k0 + 1] + x1 * nnw[2 * k1 + 1];
        float ab = x0 * nnb[k0] + x1 * nnb[k1];
        float ar = x0 * root[k0] + x1 * root[k1];
        float* y = Y + (size_t)n * 64;
        y[o] = a0; y[16 + o] = a1; y[32 + o] = ab; y[48 + o] = ar;
    }
}

// Fused: wave-per-node agg of layer l (fout=16, lrelu) -> r; next-layer
// projections -> Yout (uniform shfl broadcast of r); final-layer partial
// Y6[w][j] (+)= sum_c r_c * M3[m3base+c][j].
__global__ void aggpre16L_kernel(const int* __restrict__ rowptr, const float4* __restrict__ edata,
                                 const float* __restrict__ invdeg,
                                 const float* __restrict__ Yin, const float* __restrict__ bias,
                                 const float* __restrict__ nnw2, const float* __restrict__ nnb2,
                                 const float* __restrict__ root2,
                                 const float* __restrict__ nnw3, const float* __restrict__ nnb3,
                                 const float* __restrict__ root3,
                                 float* __restrict__ Yout, float* __restrict__ Y6,
                                 int m3base, int first, int N) {
    int w = (int)((blockIdx.x * blockDim.x + threadIdx.x) >> 6);
    if (w >= N) return;
    int lane = threadIdx.x & 63;
    int o = lane & 15, g = lane >> 4;
    int beg = rowptr[w], end = rowptr[w + 1];
    float acc = 0.f;
    for (int k = beg + g; k < end; k += 4) {
        float4 ed = edata[k];
        int s = __float_as_int(ed.x);
        const float* ys = Yin + (size_t)s * 64;
        acc += fmaf(ed.y, ys[o], fmaf(ed.z, ys[16 + o], ys[32 + o]));
    }
    acc += __shfl_xor(acc, 16, 64);
    acc += __shfl_xor(acc, 32, 64);
    float r = acc * invdeg[w] + Yin[(size_t)w * 64 + 48 + o] + bias[o];
    r = r > 0.f ? r : NEG_SLOPE * r;  // layer output, channel o in all lanes
    // next-layer projections: blk=g (0:A0 1:A1 2:B 3:root), out col = o
    {
        const float* Mp = g == 0 ? nnw2 : g == 1 ? nnw2 + 1 : g == 2 ? nnb2 : root2;
        int st = g < 2 ? 2 : 1;
        float y = 0.f;
#pragma unroll
        for (int i = 0; i < 16; ++i) {
            float xi = __shfl(r, i, 64);
            y = fmaf(xi, Mp[(i * 16 + o) * st], y);
        }
        Yout[(size_t)w * 64 + lane] = y;
    }
    // final-layer partial: j=lane&7 (blk=j>>1, oo=j&1), g8=lane>>3 owns c=2g8,2g8+1
    {
        int j = lane & 7, g8 = lane >> 3;
        int blk = j >> 1, oo = j & 1;
        const float* Mp = blk == 0 ? nnw3 : blk == 1 ? nnw3 + 1 : blk == 2 ? nnb3 : root3;
        int st = blk < 2 ? 2 : 1;
        float p = 0.f;
#pragma unroll
        for (int cc = 0; cc < 2; ++cc) {
            int c = g8 * 2 + cc;
            float xi = __shfl(r, c, 64);
            int i = m3base + c;
            p = fmaf(xi, Mp[(i * 2 + oo) * st], p);
        }
        p += __shfl_xor(p, 8, 64);
        p += __shfl_xor(p, 16, 64);
        p += __shfl_xor(p, 32, 64);
        if (lane < 8) {
            float* y6 = Y6 + (size_t)w * 8 + j;
            *y6 = first ? p : (*y6 + p);
        }
    }
}

// Layer-4: agg (lrelu) + final-layer partial only (no Yout).
__global__ void agg4_kernel(const int* __restrict__ rowptr, const float4* __restrict__ edata,
                            const float* __restrict__ invdeg,
                            const float* __restrict__ Yin, const float* __restrict__ bias,
                            const float* __restrict__ nnw3, const float* __restrict__ nnb3,
                            const float* __restrict__ root3,
                            float* __restrict__ Y6, int m3base, int N) {
    int w = (int)((blockIdx.x * blockDim.x + threadIdx.x) >> 6);
    if (w >= N) return;
    int lane = threadIdx.x & 63;
    int o = lane & 15, g = lane >> 4;
    int beg = rowptr[w], end = rowptr[w + 1];
    float acc = 0.f;
    for (int k = beg + g; k < end; k += 4) {
        float4 ed = edata[k];
        int s = __float_as_int(ed.x);
        const float* ys = Yin + (size_t)s * 64;
        acc += fmaf(ed.y, ys[o], fmaf(ed.z, ys[16 + o], ys[32 + o]));
    }
    acc += __shfl_xor(acc, 16, 64);
    acc += __shfl_xor(acc, 32, 64);
    float r = acc * invdeg[w] + Yin[(size_t)w * 64 + 48 + o] + bias[o];
    r = r > 0.f ? r : NEG_SLOPE * r;
    int j = lane & 7, g8 = lane >> 3;
    int blk = j >> 1, oo = j & 1;
    const float* Mp = blk == 0 ? nnw3 : blk == 1 ? nnw3 + 1 : blk == 2 ? nnb3 : root3;
    int st = blk < 2 ? 2 : 1;
    float p = 0.f;
#pragma unroll
    for (int cc = 0; cc < 2; ++cc) {
        int c = g8 * 2 + cc;
        float xi = __shfl(r, c, 64);
        int i = m3base + c;
        p = fmaf(xi, Mp[(i * 2 + oo) * st], p);
    }
    p += __shfl_xor(p, 8, 64);
    p += __shfl_xor(p, 16, 64);
    p += __shfl_xor(p, 32, 64);
    if (lane < 8) {
        float* y6 = Y6 + (size_t)w * 8 + j;
        *y6 = *y6 + p;
    }
}

// Final aggregation, fout=2: 64 lanes = 32 edge-groups x 2 channels.
__global__ void edge_agg2_wave(const int* __restrict__ rowptr, const float4* __restrict__ edata,
                               const float* __restrict__ invdeg,
                               const float* __restrict__ Y6, const float* __restrict__ bias,
                               float* __restrict__ Out, int N) {
    int w = (int)((blockIdx.x * blockDim.x + threadIdx.x) >> 6);
    if (w >= N) return;
    int lane = threadIdx.x & 63;
    int o = lane & 1, g = lane >> 1;
    int beg = rowptr[w], end = rowptr[w + 1];
    float acc = 0.f;
    for (int k = beg + g; k < end; k += 32) {
        float4 ed = edata[k];
        int s = __float_as_int(ed.x);
        const float* ys = Y6 + (size_t)s * 8;
        acc += fmaf(ed.y, ys[o], fmaf(ed.z, ys[2 + o], ys[4 + o]));
    }
#pragma unroll
    for (int m = 2; m <= 32; m <<= 1) acc += __shfl_xor(acc, m, 64);
    if (lane < 2) Out[(size_t)w * 2 + o] = acc * invdeg[w] + Y6[(size_t)w * 8 + 6 + o] + bias[o];
}

extern "C" void kernel_launch(void* const* d_in, const int* in_sizes, int n_in,
                              void* d_out, int out_size, void* d_ws, size_t ws_size,
                              hipStream_t stream) {
    const float* x     = (const float*)d_in[0];
    const int*   eidx  = (const int*)d_in[1];
    const float* eattr = (const float*)d_in[2];
    const float* nn1_w = (const float*)d_in[3];
    const float* nn1_b = (const float*)d_in[4];
    const float* root1 = (const float*)d_in[5];
    const float* bias1 = (const float*)d_in[6];
    const float* nn2_w = (const float*)d_in[7];
    const float* nn2_b = (const float*)d_in[8];
    const float* root2 = (const float*)d_in[9];
    const float* bias2 = (const float*)d_in[10];
    const float* nn3_w = (const float*)d_in[11];
    const float* nn3_b = (const float*)d_in[12];
    const float* root3 = (const float*)d_in[13];
    const float* bias3 = (const float*)d_in[14];
    float* out = (float*)d_out;

    const int N = in_sizes[0] / 2;
    const int E = in_sizes[2] / 2;
    const int* src = eidx;
    const int* dst = eidx + E;
    const int NB = (N + SB - 1) / SB;

    char* ws = (char*)d_ws;
    size_t off = 0;
    auto alloc = [&](size_t bytes, size_t align) -> char* {
        off = (off + align - 1) / align * align;
        char* p = ws + off;
        off += bytes;
        return p;
    };
    int*    rowptr = (int*)alloc((size_t)(N + 1) * 4, 16);
    int*    counts = (int*)alloc((size_t)N * 4, 16);
    float*  invdeg = (float*)alloc((size_t)N * 4, 16);
    int*    slot   = (int*)alloc((size_t)E * 4, 16);
    float4* edata  = (float4*)alloc((size_t)E * 16, 16);
    float*  Y_a    = (float*)alloc((size_t)N * 64 * 4, 16);
    float*  Y_b    = (float*)alloc((size_t)N * 64 * 4, 16);
    float*  Y6     = (float*)alloc((size_t)N * 8 * 4, 16);
    (void)ws_size; (void)n_in; (void)out_size;

    const int B = 256;
    auto blocks = [&](int threads) { return (threads + B - 1) / B; };
    const int waveblocks = (N * 64 + B - 1) / B;  // one wave per node
    const int nFill = blocks(E);
    const int nPre1 = blocks(N * 16);

    // --- CSR build ---
    zero1_kernel<<<blocks(N), B, 0, stream>>>(counts, N);
    count_kernel<<<blocks(E), B, 0, stream>>>(dst, counts, slot, E);
    scanall_kernel<<<NB, SB, 0, stream>>>(counts, rowptr, invdeg, N);

    // --- fill || pre1 ---
    fill_pre1_kernel<<<nFill + nPre1, B, 0, stream>>>(src, dst, eattr, rowptr, slot,
                                                      edata, E, nFill,
                                                      x, nn1_w, nn1_b, root1, Y_a, N);

    // --- layers 1-3: agg + next-layer pre + final-layer partial (ping-pong Y) ---
    aggpre16L_kernel<<<waveblocks, B, 0, stream>>>(rowptr, edata, invdeg, Y_a, bias1,
                                                   nn2_w, nn2_b, root2,
                                                   nn3_w, nn3_b, root3,
                                                   Y_b, Y6, 0, 1, N);
    aggpre16L_kernel<<<waveblocks, B, 0, stream>>>(rowptr, edata, invdeg, Y_b, bias2,
                                                   nn2_w, nn2_b, root2,
                                                   nn3_w, nn3_b, root3,
                                                   Y_a, Y6, 16, 0, N);
    aggpre16L_kernel<<<waveblocks, B, 0, stream>>>(rowptr, edata, invdeg, Y_a, bias2,
                                                   nn2_w, nn2_b, root2,
                                                   nn3_w, nn3_b, root3,
                                                   Y_b, Y6, 32, 0, N);

    // --- layer 4: agg + final-layer partial ---
    agg4_kernel<<<waveblocks, B, 0, stream>>>(rowptr, edata, invdeg, Y_b, bias2,
                                              nn3_w, nn3_b, root3, Y6, 48, N);

    // --- final aggregation (fout=2, no lrelu) ---
    edge_agg2_wave<<<waveblocks, B, 0, stream>>>(rowptr, edata, invdeg, Y6, bias3, out, N);
}